// Round 8
// baseline (141.221 us; speedup 1.0000x reference)
//
#include <hip/hip_runtime.h>
#include <hip/hip_bf16.h>
#include <cstdint>

#define NHEADS 16
#define HDIM 64
#define BB 2
#define TSEQ 2048
#define DM 1024
#define MROWS (BB*TSEQ)   // 4096

typedef unsigned short u16;
typedef unsigned int u32;
typedef __bf16 bf16x8 __attribute__((ext_vector_type(8)));
typedef float f32x4 __attribute__((ext_vector_type(4)));

#define AS1C(p) ((const __attribute__((address_space(1))) u32*)(p))
#define AS3(p)  ((__attribute__((address_space(3))) u32*)(p))

static __device__ __forceinline__ u16 f2bf(float f) {
  return __builtin_bit_cast(u16, __float2bfloat16(f));
}
static __device__ __forceinline__ float bf2f(u16 u) {
  return __bfloat162float(__builtin_bit_cast(__hip_bfloat16, u));
}
// pack two non-NaN floats to bf16 pair (round-half-up, max rel err 2^-8)
static __device__ __forceinline__ u32 pack2bf(float a, float b) {
  const u32 ua = __builtin_bit_cast(u32, a) + 0x8000u;
  const u32 ub = __builtin_bit_cast(u32, b) + 0x8000u;
  return (ua >> 16) | (ub & 0xFFFF0000u);
}
static __device__ __forceinline__ f32x4 mfma16x16(bf16x8 a, bf16x8 b, f32x4 c) {
  return __builtin_amdgcn_mfma_f32_16x16x32_bf16(a, b, c, 0, 0, 0);
}

// ---------------- fused cast fp32 -> bf16 for x, W_qkv, W_o ----------------
#define N4_X   (MROWS * DM / 4)          // 1048576
#define N4_WQ  (3 * DM * DM / 4)         // 786432
#define N4_WO  (DM * DM / 4)             // 262144
__global__ __launch_bounds__(256) void cast_all(const float* __restrict__ x,
                                                const float* __restrict__ wq,
                                                const float* __restrict__ wo,
                                                u16* __restrict__ xb,
                                                u16* __restrict__ wqb,
                                                u16* __restrict__ wob) {
  int i = blockIdx.x * 256 + threadIdx.x;
  const int stride = gridDim.x * 256;
  for (; i < N4_X + N4_WQ + N4_WO; i += stride) {
    const float4* src; u16* dst; int j;
    if (i < N4_X)            { src = (const float4*)x;  dst = xb;  j = i; }
    else if (i < N4_X + N4_WQ) { src = (const float4*)wq; dst = wqb; j = i - N4_X; }
    else                     { src = (const float4*)wo; dst = wob; j = i - N4_X - N4_WQ; }
    float4 v = src[j];
    ushort4 o;
    o.x = f2bf(v.x); o.y = f2bf(v.y); o.z = f2bf(v.z); o.w = f2bf(v.w);
    ((ushort4*)dst)[j] = o;
  }
}

// ---------------- bf16 GEMM, C[m,n] = sum_k A[m,k]*B[n,k] ----------------
template<int WRITE_BF16>
__global__ __launch_bounds__(256, 2) void gemm_bt(const u16* __restrict__ A,
                                                  const u16* __restrict__ Bm,
                                                  float* __restrict__ Cf,
                                                  u16* __restrict__ Cb,
                                                  int M, int N, int K) {
  __shared__ u16 lA[2][128 * 32];
  __shared__ u16 lB[2][128 * 32];
  const int tid = threadIdx.x;
  const int w = tid >> 6, l = tid & 63;
  const int wr = w >> 1, wc = w & 1;
  int bid = blockIdx.y * gridDim.x + blockIdx.x;
  const int cpx = (gridDim.x * gridDim.y) >> 3;
  bid = (bid & 7) * cpx + (bid >> 3);
  const int bx = bid % gridDim.x, by = bid / gridDim.x;
  const int brow = by * 128, bcol = bx * 128;
  const int lr = l & 15, lg = l >> 4;

  const int srow = l >> 2;
  const int scol = (((l & 3) ^ (srow & 3)) * 8);  // pre-swizzled source k-offset

  auto stage = [&](int buf, int k0) {
#pragma unroll
    for (int is = 0; is < 2; ++is) {
      const int chunk = w * 2 + is;
      const int row = chunk * 16 + srow;
      __builtin_amdgcn_global_load_lds(AS1C(A + (size_t)(brow + row) * K + k0 + scol),
                                       AS3((char*)lA[buf] + chunk * 1024), 16, 0, 0);
      __builtin_amdgcn_global_load_lds(AS1C(Bm + (size_t)(bcol + row) * K + k0 + scol),
                                       AS3((char*)lB[buf] + chunk * 1024), 16, 0, 0);
    }
  };

  f32x4 acc[4][4] = {};
  const int nk = K >> 5;
  stage(0, 0);
  for (int kk = 0; kk < nk; ++kk) {
    const int cur = kk & 1;
    __syncthreads();
    if (kk + 1 < nk) stage(cur ^ 1, (kk + 1) << 5);
    bf16x8 af[4], bfr[4];
#pragma unroll
    for (int m = 0; m < 4; ++m) {
      const int row = wr * 64 + m * 16 + lr;
      const int sl = lg ^ (row & 3);
      af[m] = *(const bf16x8*)(&lA[cur][row * 32 + sl * 8]);
    }
#pragma unroll
    for (int n = 0; n < 4; ++n) {
      const int row = wc * 64 + n * 16 + lr;
      const int sl = lg ^ (row & 3);
      bfr[n] = *(const bf16x8*)(&lB[cur][row * 32 + sl * 8]);
    }
#pragma unroll
    for (int m = 0; m < 4; ++m)
#pragma unroll
      for (int n = 0; n < 4; ++n)
        acc[m][n] = mfma16x16(af[m], bfr[n], acc[m][n]);
  }
#pragma unroll
  for (int m = 0; m < 4; ++m)
#pragma unroll
    for (int n = 0; n < 4; ++n)
#pragma unroll
      for (int r = 0; r < 4; ++r) {
        const int row = brow + wr * 64 + m * 16 + lg * 4 + r;
        const int col = bcol + wc * 64 + n * 16 + lr;
        if constexpr (WRITE_BF16)
          Cb[(size_t)row * N + col] = f2bf(acc[m][n][r]);
        else
          Cf[(size_t)row * N + col] = acc[m][n][r];
      }
}

// ---------------- RoPE + reshape ----------------
// q is pre-scaled by (1/8)*log2(e) so attention scores arrive in the log2
// domain and the softmax exp becomes a raw v_exp_f32.
__global__ __launch_bounds__(256) void rope_reshape(const u16* __restrict__ qkvb,
                                                    u16* __restrict__ qb,
                                                    u16* __restrict__ kb,
                                                    u16* __restrict__ vbT) {
  const int bh = blockIdx.y;
  const int b = bh >> 4, h = bh & 15;
  const int t0 = blockIdx.x * 64;
  const int tid = threadIdx.x;
  const float C = -0.4152410118609203f;  // -log2(10000)/32
  const float QS = 0.125f * 1.44269504088896341f;

  for (int idx = tid; idx < 64 * 32; idx += 256) {
    const int tl = idx >> 5, p = idx & 31;
    const int t = t0 + tl;
    const size_t base = ((size_t)(b * TSEQ + t)) * 3072 + h * 64 + 2 * p;
    const float qe = bf2f(qkvb[base]), qo = bf2f(qkvb[base + 1]);
    const float ke = bf2f(qkvb[base + 1024]), ko = bf2f(qkvb[base + 1025]);
    const float inv = exp2f((float)p * C);
    const float ang = (float)t * inv;
    float sn, cs;
    sincosf(ang, &sn, &cs);
    const size_t ob = ((size_t)bh * TSEQ + t) * 64 + 2 * p;
    qb[ob]     = f2bf((qe * cs - qo * sn) * QS);
    qb[ob + 1] = f2bf((qe * sn + qo * cs) * QS);
    kb[ob]     = f2bf(ke * cs - ko * sn);
    kb[ob + 1] = f2bf(ke * sn + ko * cs);
  }

  __shared__ u16 lT[64][65];
  for (int idx = tid; idx < 64 * 64; idx += 256) {
    const int tl = idx >> 6, d = idx & 63;
    lT[tl][d] = qkvb[((size_t)(b * TSEQ + t0 + tl)) * 3072 + 2048 + h * 64 + d];
  }
  __syncthreads();
  for (int idx = tid; idx < 64 * 64; idx += 256) {
    const int d = idx >> 6, tl = idx & 63;
    vbT[((size_t)bh * 64 + d) * TSEQ + t0 + tl] = lT[tl][d];
  }
}

// ---------------- causal flash attention (barrier-free, L2-direct) --------
// K/V per head (512KB) is L2-resident on its XCD (swizzle below), so no LDS
// staging: K/V fragments load DIRECTLY global->VGPR (L2 hits). No
// __syncthreads() anywhere; waves fully independent. Each wave owns 32
// q-rows (chunk c: rows [32c,32c+32)), walks kv-tiles 0..c/2. Block = 4
// waves, chunks {2k,2k+1,62-2k,63-2k} -> 66 tile-iters/block uniform; paired
// waves walk the same kv-tiles in near-sync -> L1 catches repeats.
// Only P round-trips through wave-private LDS (2KB, lgkmcnt-ordered).
__global__ __launch_bounds__(256, 2) void attn_fwd(const u16* __restrict__ qb,
                                                   const u16* __restrict__ kb,
                                                   const u16* __restrict__ vbT,
                                                   u16* __restrict__ ob) {
  __shared__ u16 lP[4][16 * 64];          // 8KB total, 2KB per wave
  const int hw = blockIdx.x;
  const int logical = (hw & 7) * 64 + (hw >> 3);  // 8 XCDs x 64 blocks
  const int bh = logical >> 4;            // 4 consecutive heads per XCD
  const int k16 = logical & 15;
  const int b = bh >> 4, h = bh & 15;
  const int w = threadIdx.x >> 6, l = threadIdx.x & 63;
  const int lr = l & 15, lg = l >> 4;
  // wave's q-chunk: {2k,2k+1, 62-2k,63-2k}
  const int c = (w < 2) ? (2 * k16 + w) : (62 - 2 * k16 + (w - 2));
  const int q0 = c * 32;
  const int nt = (c >> 1) + 1;
  const int dtile = c >> 1;
  const int qa0 = q0 + lr;                // sub0 absolute q row
  const u16* Kb = kb + (size_t)bh * TSEQ * 64;
  const u16* Vb = vbT + (size_t)bh * 64 * TSEQ;
  u16* lPw = lP[w];

  // Q: 32 rows, loaded once (16 VGPRs)
  bf16x8 qf[2][2];
  {
    const u16* qp = qb + ((size_t)bh * TSEQ + q0 + lr) * 64 + lg * 8;
    qf[0][0] = *(const bf16x8*)qp;
    qf[0][1] = *(const bf16x8*)(qp + 32);
    qp += 16 * 64;
    qf[1][0] = *(const bf16x8*)qp;
    qf[1][1] = *(const bf16x8*)(qp + 32);
  }

  f32x4 o0[4] = {}, o1[4] = {};
  float ls0 = 0.f, ls1 = 0.f;

  // per-lane base pointers (fragment slot: row +lr, col (ks*4+lg)*8)
  const u16* kp = Kb + (size_t)lr * 64 + lg * 8;          // + kt*4096 per tile
  const u16* vp = Vb + (size_t)lr * TSEQ + lg * 8;        // + kt*64 per tile

  for (int kt = 0; kt < nt; ++kt) {
    // K fragments: row = kt*64 + n*16 + lr, col (ks*4+lg)*8
    bf16x8 kf[4][2], vf[4][2];
#pragma unroll
    for (int n = 0; n < 4; ++n)
#pragma unroll
      for (int ks = 0; ks < 2; ++ks)
        kf[n][ks] = *(const bf16x8*)(kp + (size_t)kt * 4096 + n * 1024 + ks * 32);
    // V fragments: row = n*16 + lr (d), col = kt*64 + (ks*4+lg)*8 (t)
#pragma unroll
    for (int n = 0; n < 4; ++n)
#pragma unroll
      for (int ks = 0; ks < 2; ++ks)
        vf[n][ks] = *(const bf16x8*)(vp + (size_t)n * 16 * TSEQ + kt * 64 + ks * 32);

    // S^T = K Q^T for both q-sub-tiles
    f32x4 s0[4] = {}, s1[4] = {};
    __builtin_amdgcn_s_setprio(1);
#pragma unroll
    for (int n = 0; n < 4; ++n)
#pragma unroll
      for (int ks = 0; ks < 2; ++ks) {
        s0[n] = mfma16x16(kf[n][ks], qf[0][ks], s0[n]);
        s1[n] = mfma16x16(kf[n][ks], qf[1][ks], s1[n]);
      }
    __builtin_amdgcn_s_setprio(0);

    const bool diag = (kt == dtile);
    const int kvb = kt * 64;

    // qsub0: P = exp2(s), mask, pack -> wave-private LDS; read pf0
#pragma unroll
    for (int n = 0; n < 4; ++n) {
      float pv[4];
#pragma unroll
      for (int r = 0; r < 4; ++r) {
        float p = __builtin_amdgcn_exp2f(s0[n][r]);
        if (diag && (kvb + n * 16 + lg * 4 + r > qa0)) p = 0.f;
        pv[r] = p;
        ls0 += p;
      }
      const int phys = (n * 2 + (lg >> 1)) ^ (lr & 7);
      uint2 pk; pk.x = pack2bf(pv[0], pv[1]); pk.y = pack2bf(pv[2], pv[3]);
      *(uint2*)(&lPw[lr * 64 + phys * 8 + (lg & 1) * 4]) = pk;
    }
    bf16x8 pf0[2];
#pragma unroll
    for (int ks = 0; ks < 2; ++ks) {
      const int phys = (ks * 4 + lg) ^ (lr & 7);
      pf0[ks] = *(const bf16x8*)(&lPw[lr * 64 + phys * 8]);
    }

    // qsub1: reuse the same 2KB buffer (wave-ordered DS ops)
#pragma unroll
    for (int n = 0; n < 4; ++n) {
      float pv[4];
#pragma unroll
      for (int r = 0; r < 4; ++r) {
        float p = __builtin_amdgcn_exp2f(s1[n][r]);
        if (diag && (kvb + n * 16 + lg * 4 + r > qa0 + 16)) p = 0.f;
        pv[r] = p;
        ls1 += p;
      }
      const int phys = (n * 2 + (lg >> 1)) ^ (lr & 7);
      uint2 pk; pk.x = pack2bf(pv[0], pv[1]); pk.y = pack2bf(pv[2], pv[3]);
      *(uint2*)(&lPw[lr * 64 + phys * 8 + (lg & 1) * 4]) = pk;
    }
    bf16x8 pf1[2];
#pragma unroll
    for (int ks = 0; ks < 2; ++ks) {
      const int phys = (ks * 4 + lg) ^ (lr & 7);
      pf1[ks] = *(const bf16x8*)(&lPw[lr * 64 + phys * 8]);
    }

    // O^T += V P^T for both sub-tiles, single V fragment pass
    __builtin_amdgcn_s_setprio(1);
#pragma unroll
    for (int n = 0; n < 4; ++n)
#pragma unroll
      for (int ks = 0; ks < 2; ++ks) {
        o0[n] = mfma16x16(vf[n][ks], pf0[ks], o0[n]);
        o1[n] = mfma16x16(vf[n][ks], pf1[ks], o1[n]);
      }
    __builtin_amdgcn_s_setprio(0);
  }

  // full row sums (per-lane q=lr after reduce)
  ls0 += __shfl_xor(ls0, 16); ls0 += __shfl_xor(ls0, 32);
  ls1 += __shfl_xor(ls1, 16); ls1 += __shfl_xor(ls1, 32);

  const float rl0 = 1.f / ls0, rl1 = 1.f / ls1;
#pragma unroll
  for (int qs = 0; qs < 2; ++qs) {
    const int q = q0 + qs * 16 + lr;
    const float rl = qs ? rl1 : rl0;
#pragma unroll
    for (int n = 0; n < 4; ++n) {
      ushort4 ov;
#pragma unroll
      for (int r = 0; r < 4; ++r) {
        const float o = qs ? o1[n][r] : o0[n][r];
        ((u16*)&ov)[r] = f2bf(o * rl);
      }
      *(ushort4*)(&ob[(size_t)(b * TSEQ + q) * DM + h * 64 + n * 16 + lg * 4]) = ov;
    }
  }
}

// ---------------- launch ----------------
extern "C" void kernel_launch(void* const* d_in, const int* in_sizes, int n_in,
                              void* d_out, int out_size, void* d_ws, size_t ws_size,
                              hipStream_t stream) {
  const float* x    = (const float*)d_in[0];
  const float* Wqkv = (const float*)d_in[1];
  const float* Wo   = (const float*)d_in[2];
  float* out = (float*)d_out;

  char* ws = (char*)d_ws;
  u16* xb    = (u16*)ws; ws += (size_t)MROWS * DM * 2;
  u16* wqkvb = (u16*)ws; ws += (size_t)3 * DM * DM * 2;
  u16* wob   = (u16*)ws; ws += (size_t)DM * DM * 2;
  u16* qkvb  = (u16*)ws; ws += (size_t)MROWS * 3 * DM * 2;
  u16* qb    = (u16*)ws; ws += (size_t)BB * NHEADS * TSEQ * HDIM * 2;
  u16* kb    = (u16*)ws; ws += (size_t)BB * NHEADS * TSEQ * HDIM * 2;
  u16* vbT   = (u16*)ws; ws += (size_t)BB * NHEADS * TSEQ * HDIM * 2;
  u16* ob    = (u16*)ws; ws += (size_t)MROWS * DM * 2;

  cast_all<<<2048, 256, 0, stream>>>(x, Wqkv, Wo, xb, wqkvb, wob);

  gemm_bt<1><<<dim3(3 * DM / 128, MROWS / 128), 256, 0, stream>>>(
      xb, wqkvb, nullptr, qkvb, MROWS, 3 * DM, DM);

  rope_reshape<<<dim3(TSEQ / 64, BB * NHEADS), 256, 0, stream>>>(qkvb, qb, kb, vbT);

  attn_fwd<<<512, 256, 0, stream>>>(qb, kb, vbT, ob);

  gemm_bt<0><<<dim3(DM / 128, MROWS / 128), 256, 0, stream>>>(
      ob, wob, out, nullptr, MROWS, DM, DM);
}

// Round 9
// 115.618 us; speedup vs baseline: 1.2214x; 1.2214x over previous
//
#include <hip/hip_runtime.h>
#include <hip/hip_bf16.h>
#include <cstdint>

#define NHEADS 16
#define HDIM 64
#define BB 2
#define TSEQ 2048
#define DM 1024
#define MROWS (BB*TSEQ)   // 4096

typedef unsigned short u16;
typedef unsigned int u32;
typedef __bf16 bf16x8 __attribute__((ext_vector_type(8)));
typedef float f32x4 __attribute__((ext_vector_type(4)));

#define AS1C(p) ((const __attribute__((address_space(1))) u32*)(p))
#define AS3(p)  ((__attribute__((address_space(3))) u32*)(p))

static __device__ __forceinline__ u16 f2bf(float f) {
  return __builtin_bit_cast(u16, __float2bfloat16(f));
}
static __device__ __forceinline__ float bf2f(u16 u) {
  return __bfloat162float(__builtin_bit_cast(__hip_bfloat16, u));
}
// pack two non-NaN floats to bf16 pair (round-half-up, max rel err 2^-8)
static __device__ __forceinline__ u32 pack2bf(float a, float b) {
  const u32 ua = __builtin_bit_cast(u32, a) + 0x8000u;
  const u32 ub = __builtin_bit_cast(u32, b) + 0x8000u;
  return (ua >> 16) | (ub & 0xFFFF0000u);
}
static __device__ __forceinline__ f32x4 mfma16x16(bf16x8 a, bf16x8 b, f32x4 c) {
  return __builtin_amdgcn_mfma_f32_16x16x32_bf16(a, b, c, 0, 0, 0);
}

// ---------------- fused cast fp32 -> bf16 for x, W_qkv, W_o ----------------
#define N4_X   (MROWS * DM / 4)          // 1048576
#define N4_WQ  (3 * DM * DM / 4)         // 786432
#define N4_WO  (DM * DM / 4)             // 262144
__global__ __launch_bounds__(256) void cast_all(const float* __restrict__ x,
                                                const float* __restrict__ wq,
                                                const float* __restrict__ wo,
                                                u16* __restrict__ xb,
                                                u16* __restrict__ wqb,
                                                u16* __restrict__ wob) {
  int i = blockIdx.x * 256 + threadIdx.x;
  const int stride = gridDim.x * 256;
  for (; i < N4_X + N4_WQ + N4_WO; i += stride) {
    const float4* src; u16* dst; int j;
    if (i < N4_X)            { src = (const float4*)x;  dst = xb;  j = i; }
    else if (i < N4_X + N4_WQ) { src = (const float4*)wq; dst = wqb; j = i - N4_X; }
    else                     { src = (const float4*)wo; dst = wob; j = i - N4_X - N4_WQ; }
    float4 v = src[j];
    ushort4 o;
    o.x = f2bf(v.x); o.y = f2bf(v.y); o.z = f2bf(v.z); o.w = f2bf(v.w);
    ((ushort4*)dst)[j] = o;
  }
}

// ---------------- bf16 GEMM, C[m,n] = sum_k A[m,k]*B[n,k] ----------------
template<int WRITE_BF16>
__global__ __launch_bounds__(256, 2) void gemm_bt(const u16* __restrict__ A,
                                                  const u16* __restrict__ Bm,
                                                  float* __restrict__ Cf,
                                                  u16* __restrict__ Cb,
                                                  int M, int N, int K) {
  __shared__ u16 lA[2][128 * 32];
  __shared__ u16 lB[2][128 * 32];
  const int tid = threadIdx.x;
  const int w = tid >> 6, l = tid & 63;
  const int wr = w >> 1, wc = w & 1;
  int bid = blockIdx.y * gridDim.x + blockIdx.x;
  const int cpx = (gridDim.x * gridDim.y) >> 3;
  bid = (bid & 7) * cpx + (bid >> 3);
  const int bx = bid % gridDim.x, by = bid / gridDim.x;
  const int brow = by * 128, bcol = bx * 128;
  const int lr = l & 15, lg = l >> 4;

  const int srow = l >> 2;
  const int scol = (((l & 3) ^ (srow & 3)) * 8);  // pre-swizzled source k-offset

  auto stage = [&](int buf, int k0) {
#pragma unroll
    for (int is = 0; is < 2; ++is) {
      const int chunk = w * 2 + is;
      const int row = chunk * 16 + srow;
      __builtin_amdgcn_global_load_lds(AS1C(A + (size_t)(brow + row) * K + k0 + scol),
                                       AS3((char*)lA[buf] + chunk * 1024), 16, 0, 0);
      __builtin_amdgcn_global_load_lds(AS1C(Bm + (size_t)(bcol + row) * K + k0 + scol),
                                       AS3((char*)lB[buf] + chunk * 1024), 16, 0, 0);
    }
  };

  f32x4 acc[4][4] = {};
  const int nk = K >> 5;
  stage(0, 0);
  for (int kk = 0; kk < nk; ++kk) {
    const int cur = kk & 1;
    __syncthreads();
    if (kk + 1 < nk) stage(cur ^ 1, (kk + 1) << 5);
    bf16x8 af[4], bfr[4];
#pragma unroll
    for (int m = 0; m < 4; ++m) {
      const int row = wr * 64 + m * 16 + lr;
      const int sl = lg ^ (row & 3);
      af[m] = *(const bf16x8*)(&lA[cur][row * 32 + sl * 8]);
    }
#pragma unroll
    for (int n = 0; n < 4; ++n) {
      const int row = wc * 64 + n * 16 + lr;
      const int sl = lg ^ (row & 3);
      bfr[n] = *(const bf16x8*)(&lB[cur][row * 32 + sl * 8]);
    }
#pragma unroll
    for (int m = 0; m < 4; ++m)
#pragma unroll
      for (int n = 0; n < 4; ++n)
        acc[m][n] = mfma16x16(af[m], bfr[n], acc[m][n]);
  }
#pragma unroll
  for (int m = 0; m < 4; ++m)
#pragma unroll
    for (int n = 0; n < 4; ++n)
#pragma unroll
      for (int r = 0; r < 4; ++r) {
        const int row = brow + wr * 64 + m * 16 + lg * 4 + r;
        const int col = bcol + wc * 64 + n * 16 + lr;
        if constexpr (WRITE_BF16)
          Cb[(size_t)row * N + col] = f2bf(acc[m][n][r]);
        else
          Cf[(size_t)row * N + col] = acc[m][n][r];
      }
}

// ---------------- RoPE + reshape ----------------
// q is pre-scaled by (1/8)*log2(e) so attention scores arrive in the log2
// domain and the softmax exp becomes a raw v_exp_f32.
__global__ __launch_bounds__(256) void rope_reshape(const u16* __restrict__ qkvb,
                                                    u16* __restrict__ qb,
                                                    u16* __restrict__ kb,
                                                    u16* __restrict__ vbT) {
  const int bh = blockIdx.y;
  const int b = bh >> 4, h = bh & 15;
  const int t0 = blockIdx.x * 64;
  const int tid = threadIdx.x;
  const float C = -0.4152410118609203f;  // -log2(10000)/32
  const float QS = 0.125f * 1.44269504088896341f;

  for (int idx = tid; idx < 64 * 32; idx += 256) {
    const int tl = idx >> 5, p = idx & 31;
    const int t = t0 + tl;
    const size_t base = ((size_t)(b * TSEQ + t)) * 3072 + h * 64 + 2 * p;
    const float qe = bf2f(qkvb[base]), qo = bf2f(qkvb[base + 1]);
    const float ke = bf2f(qkvb[base + 1024]), ko = bf2f(qkvb[base + 1025]);
    const float inv = exp2f((float)p * C);
    const float ang = (float)t * inv;
    float sn, cs;
    sincosf(ang, &sn, &cs);
    const size_t ob = ((size_t)bh * TSEQ + t) * 64 + 2 * p;
    qb[ob]     = f2bf((qe * cs - qo * sn) * QS);
    qb[ob + 1] = f2bf((qe * sn + qo * cs) * QS);
    kb[ob]     = f2bf(ke * cs - ko * sn);
    kb[ob + 1] = f2bf(ke * sn + ko * cs);
  }

  __shared__ u16 lT[64][65];
  for (int idx = tid; idx < 64 * 64; idx += 256) {
    const int tl = idx >> 6, d = idx & 63;
    lT[tl][d] = qkvb[((size_t)(b * TSEQ + t0 + tl)) * 3072 + 2048 + h * 64 + d];
  }
  __syncthreads();
  for (int idx = tid; idx < 64 * 64; idx += 256) {
    const int d = idx >> 6, tl = idx & 63;
    vbT[((size_t)bh * 64 + d) * TSEQ + t0 + tl] = lT[tl][d];
  }
}

// ---------------- causal flash attention (R5 skeleton + 32q/wave) ---------
// 512 blocks x 256 thr (4 waves: 2 q-waves x 2 kv-groups), 2 blocks/CU so
// one block's barrier drain hides under the other's compute (R5's recipe).
// Block = q-tile pair {qt, 31-qt} (64 rows each) -> exactly 33 kv-tile
// computations/block, uniform. Each wave owns 32 q-rows (2 sub-tiles of 16):
// every K/V fragment read from LDS feeds 2 MFMAs -> DS traffic per work
// halves vs R5. Groups process even/odd kv tiles; O/l merged through LDS.
// XCD swizzle: each XCD owns 4 consecutive heads (K/V L2-resident).
__global__ __launch_bounds__(256, 2) void attn_fwd(const u16* __restrict__ qb,
                                                   const u16* __restrict__ kb,
                                                   const u16* __restrict__ vbT,
                                                   u16* __restrict__ ob) {
  __shared__ u16 lK[2][2][64 * 64];   // [group][buf] 32KB
  __shared__ u16 lV[2][2][64 * 64];   // 32KB
  __shared__ u16 lP[4][16 * 64];      // 8KB (2KB/wave)
  const int hw = blockIdx.x;
  const int logical = (hw & 7) * 64 + (hw >> 3);  // 8 XCDs x 64 blocks
  const int bh = logical >> 4;            // 4 consecutive heads per XCD
  const int pair = logical & 15;          // q-tile pair {pair, 31-pair}
  const int b = bh >> 4, h = bh & 15;
  const int tid = threadIdx.x;
  const int w = tid >> 6, l = tid & 63;
  const int g = w >> 1, wq = w & 1;       // kv-group, q-wave within group
  const int lr = l & 15, lg = l >> 4;
  const int srow8 = l >> 3;
  const int scol = ((l & 7) ^ srow8) * 8; // pre-swizzled source col (elems)
  const u16* Kb = kb + (size_t)bh * TSEQ * 64;
  const u16* Vb = vbT + (size_t)bh * 64 * TSEQ;
  u16* lPw = lP[w];

  auto stage = [&](int buf, int kt) {
#pragma unroll
    for (int is = 0; is < 4; ++is) {
      const int chunk = wq * 4 + is;           // 0..7, 1KB each
      const int row = chunk * 8 + srow8;       // 0..63
      __builtin_amdgcn_global_load_lds(AS1C(Kb + (size_t)(kt * 64 + row) * 64 + scol),
                                       AS3((char*)lK[g][buf] + chunk * 1024), 16, 0, 0);
      __builtin_amdgcn_global_load_lds(AS1C(Vb + (size_t)row * TSEQ + kt * 64 + scol),
                                       AS3((char*)lV[g][buf] + chunk * 1024), 16, 0, 0);
    }
  };

  for (int half = 0; half < 2; ++half) {
    const int qt = half ? (31 - pair) : pair;
    const int q0 = qt * 64;
    const int nt = qt + 1;
    const int nit = (nt + 1) >> 1;
    const int qa0 = q0 + wq * 32 + lr;    // qsub0 absolute q row

    bf16x8 qf[2][2];
    {
      const u16* qp = qb + ((size_t)bh * TSEQ + q0 + wq * 32 + lr) * 64 + lg * 8;
      qf[0][0] = *(const bf16x8*)qp;
      qf[0][1] = *(const bf16x8*)(qp + 32);
      qp += 16 * 64;
      qf[1][0] = *(const bf16x8*)qp;
      qf[1][1] = *(const bf16x8*)(qp + 32);
    }

    f32x4 o0[4] = {}, o1[4] = {};
    float ls0 = 0.f, ls1 = 0.f;

    __syncthreads();                  // prev half's merge reads done; LDS free
    if (g < nt) stage(0, g);
    for (int it = 0; it < nit; ++it) {
      const int cur = it & 1;
      __syncthreads();                // staged buf[cur] visible
      const int ktn = 2 * (it + 1) + g;
      if (ktn < nt) stage(cur ^ 1, ktn);
      const int kt = 2 * it + g;
      if (kt < nt) {
        const u16* Kc = lK[g][cur];
        const u16* Vc = lV[g][cur];

        // S^T = K Q^T for both q-sub-tiles, sharing the K fragments
        f32x4 s0[4] = {}, s1[4] = {};
        __builtin_amdgcn_s_setprio(1);
#pragma unroll
        for (int n = 0; n < 4; ++n) {
          const int row = n * 16 + lr;
#pragma unroll
          for (int ks = 0; ks < 2; ++ks) {
            const int sl = (ks * 4 + lg) ^ (row & 7);
            bf16x8 kf = *(const bf16x8*)(&Kc[row * 64 + sl * 8]);
            s0[n] = mfma16x16(kf, qf[0][ks], s0[n]);
            s1[n] = mfma16x16(kf, qf[1][ks], s1[n]);
          }
        }
        __builtin_amdgcn_s_setprio(0);

        const bool diag = (kt == qt);
        const int kvb = kt * 64;

        // qsub0: P = exp2(s), mask, pack -> lPw; read pf0
#pragma unroll
        for (int n = 0; n < 4; ++n) {
          float pv[4];
#pragma unroll
          for (int r = 0; r < 4; ++r) {
            float p = __builtin_amdgcn_exp2f(s0[n][r]);
            if (diag && (kvb + n * 16 + lg * 4 + r > qa0)) p = 0.f;
            pv[r] = p;
            ls0 += p;
          }
          const int phys = (n * 2 + (lg >> 1)) ^ (lr & 7);
          uint2 pk; pk.x = pack2bf(pv[0], pv[1]); pk.y = pack2bf(pv[2], pv[3]);
          *(uint2*)(&lPw[lr * 64 + phys * 8 + (lg & 1) * 4]) = pk;
        }
        bf16x8 pf0[2];
#pragma unroll
        for (int ks = 0; ks < 2; ++ks) {
          const int phys = (ks * 4 + lg) ^ (lr & 7);
          pf0[ks] = *(const bf16x8*)(&lPw[lr * 64 + phys * 8]);
        }

        // qsub1: reuse the same 2KB P buffer (wave-ordered DS ops)
#pragma unroll
        for (int n = 0; n < 4; ++n) {
          float pv[4];
#pragma unroll
          for (int r = 0; r < 4; ++r) {
            float p = __builtin_amdgcn_exp2f(s1[n][r]);
            if (diag && (kvb + n * 16 + lg * 4 + r > qa0 + 16)) p = 0.f;
            pv[r] = p;
            ls1 += p;
          }
          const int phys = (n * 2 + (lg >> 1)) ^ (lr & 7);
          uint2 pk; pk.x = pack2bf(pv[0], pv[1]); pk.y = pack2bf(pv[2], pv[3]);
          *(uint2*)(&lPw[lr * 64 + phys * 8 + (lg & 1) * 4]) = pk;
        }
        bf16x8 pf1[2];
#pragma unroll
        for (int ks = 0; ks < 2; ++ks) {
          const int phys = (ks * 4 + lg) ^ (lr & 7);
          pf1[ks] = *(const bf16x8*)(&lPw[lr * 64 + phys * 8]);
        }

        // O^T += V P^T for both sub-tiles, single V fragment pass
        __builtin_amdgcn_s_setprio(1);
#pragma unroll
        for (int n = 0; n < 4; ++n) {
          const int row = n * 16 + lr;
#pragma unroll
          for (int ks = 0; ks < 2; ++ks) {
            const int sl = (ks * 4 + lg) ^ (row & 7);
            bf16x8 vf = *(const bf16x8*)(&Vc[row * 64 + sl * 8]);
            o0[n] = mfma16x16(vf, pf0[ks], o0[n]);
            o1[n] = mfma16x16(vf, pf1[ks], o1[n]);
          }
        }
        __builtin_amdgcn_s_setprio(0);
      }
    }

    // full row sums (per-lane q=lr after reduce)
    ls0 += __shfl_xor(ls0, 16); ls0 += __shfl_xor(ls0, 32);
    ls1 += __shfl_xor(ls1, 16); ls1 += __shfl_xor(ls1, 32);

    // merge the two kv-groups' (O, l) through LDS
    __syncthreads();
    float* mO = (float*)&lK[0][0][0];   // [2 wq][2 qs][64 d][16 lr] f32 = 16KB
    float* mL = (float*)&lV[0][0][0];   // [2 wq][2 qs][16 lr]
    if (g == 1) {
#pragma unroll
      for (int qs = 0; qs < 2; ++qs)
#pragma unroll
        for (int n = 0; n < 4; ++n)
#pragma unroll
          for (int r = 0; r < 4; ++r) {
            const int d = n * 16 + lg * 4 + r;
            mO[((wq * 2 + qs) * 64 + d) * 16 + lr] = (qs ? o1[n][r] : o0[n][r]);
          }
      if (lg == 0) {
        mL[(wq * 2 + 0) * 16 + lr] = ls0;
        mL[(wq * 2 + 1) * 16 + lr] = ls1;
      }
    }
    __syncthreads();
    if (g == 0) {
      const float rl0 = 1.f / (ls0 + mL[(wq * 2 + 0) * 16 + lr]);
      const float rl1 = 1.f / (ls1 + mL[(wq * 2 + 1) * 16 + lr]);
#pragma unroll
      for (int qs = 0; qs < 2; ++qs) {
        const int q = q0 + wq * 32 + qs * 16 + lr;
        const float rl = qs ? rl1 : rl0;
#pragma unroll
        for (int n = 0; n < 4; ++n) {
          ushort4 ov;
#pragma unroll
          for (int r = 0; r < 4; ++r) {
            const int d = n * 16 + lg * 4 + r;
            const float o = (qs ? o1[n][r] : o0[n][r]) + mO[((wq * 2 + qs) * 64 + d) * 16 + lr];
            ((u16*)&ov)[r] = f2bf(o * rl);
          }
          *(ushort4*)(&ob[(size_t)(b * TSEQ + q) * DM + h * 64 + n * 16 + lg * 4]) = ov;
        }
      }
    }
  }
}

// ---------------- launch ----------------
extern "C" void kernel_launch(void* const* d_in, const int* in_sizes, int n_in,
                              void* d_out, int out_size, void* d_ws, size_t ws_size,
                              hipStream_t stream) {
  const float* x    = (const float*)d_in[0];
  const float* Wqkv = (const float*)d_in[1];
  const float* Wo   = (const float*)d_in[2];
  float* out = (float*)d_out;

  char* ws = (char*)d_ws;
  u16* xb    = (u16*)ws; ws += (size_t)MROWS * DM * 2;
  u16* wqkvb = (u16*)ws; ws += (size_t)3 * DM * DM * 2;
  u16* wob   = (u16*)ws; ws += (size_t)DM * DM * 2;
  u16* qkvb  = (u16*)ws; ws += (size_t)MROWS * 3 * DM * 2;
  u16* qb    = (u16*)ws; ws += (size_t)BB * NHEADS * TSEQ * HDIM * 2;
  u16* kb    = (u16*)ws; ws += (size_t)BB * NHEADS * TSEQ * HDIM * 2;
  u16* vbT   = (u16*)ws; ws += (size_t)BB * NHEADS * TSEQ * HDIM * 2;
  u16* ob    = (u16*)ws; ws += (size_t)MROWS * DM * 2;

  cast_all<<<2048, 256, 0, stream>>>(x, Wqkv, Wo, xb, wqkvb, wob);

  gemm_bt<1><<<dim3(3 * DM / 128, MROWS / 128), 256, 0, stream>>>(
      xb, wqkvb, nullptr, qkvb, MROWS, 3 * DM, DM);

  rope_reshape<<<dim3(TSEQ / 64, BB * NHEADS), 256, 0, stream>>>(qkvb, qb, kb, vbT);

  attn_fwd<<<512, 256, 0, stream>>>(qb, kb, vbT, ob);

  gemm_bt<0><<<dim3(DM / 128, MROWS / 128), 256, 0, stream>>>(
      ob, wob, out, nullptr, MROWS, DM, DM);
}